// Round 1
// baseline (325.144 us; speedup 1.0000x reference)
//
#include <hip/hip_runtime.h>

#define DIM 128

typedef _Float16 half8 __attribute__((ext_vector_type(8)));
typedef float floatx4 __attribute__((ext_vector_type(4)));

// ---------------- CSR build ----------------
__global__ void k_degree(const int* __restrict__ dst, int* __restrict__ deg, int E){
  int e = blockIdx.x*256 + threadIdx.x;
  if (e < E) atomicAdd(&deg[dst[e]], 1);
}

__global__ void k_scan1(const int* __restrict__ deg, int* __restrict__ rowStart,
                        int* __restrict__ blockSums, int n){
  __shared__ int sm[16];
  int i = blockIdx.x*1024 + threadIdx.x;
  int v = (i < n) ? deg[i] : 0;
  int lane = threadIdx.x & 63, wid = threadIdx.x >> 6;
  int x = v;
  #pragma unroll
  for (int off = 1; off < 64; off <<= 1){
    int y = __shfl_up(x, off);
    if (lane >= off) x += y;
  }
  if (lane == 63) sm[wid] = x;
  __syncthreads();
  if (threadIdx.x < 64){
    int s = (lane < 16) ? sm[lane] : 0;
    #pragma unroll
    for (int off = 1; off < 16; off <<= 1){
      int y = __shfl_up(s, off);
      if (lane >= off) s += y;
    }
    if (lane < 16) sm[lane] = s;
  }
  __syncthreads();
  int base = (wid > 0) ? sm[wid-1] : 0;
  if (i < n) rowStart[i] = base + x - v;      // block-local exclusive
  if (threadIdx.x == 1023) blockSums[blockIdx.x] = sm[15];
}

__global__ void k_scan2(int* blockSums, int nb){   // 1 block, 64 threads, nb<=64
  int lane = threadIdx.x;
  int v = (lane < nb) ? blockSums[lane] : 0;
  int x = v;
  #pragma unroll
  for (int off = 1; off < 64; off <<= 1){
    int y = __shfl_up(x, off);
    if (lane >= off) x += y;
  }
  if (lane < nb) blockSums[lane] = x - v;     // exclusive
}

__global__ void k_scan3(int* __restrict__ rowStart, const int* __restrict__ blockSums,
                        int* __restrict__ fill, float* __restrict__ invdeg,
                        const int* __restrict__ deg, int n, int Etot){
  int i = blockIdx.x*1024 + threadIdx.x;
  if (i < n){
    int r = rowStart[i] + blockSums[i >> 10];
    rowStart[i] = r;
    fill[i] = r;
    invdeg[i] = 1.0f / fmaxf((float)deg[i], 1.0f);
  }
  if (i == 0) rowStart[n] = Etot;
}

__global__ void k_scatter(const int* __restrict__ src, const int* __restrict__ dst,
                          int* __restrict__ fill, int* __restrict__ srcIdx, int E){
  int e = blockIdx.x*256 + threadIdx.x;
  if (e < E){
    int p = atomicAdd(&fill[dst[e]], 1);
    srcIdx[p] = src[e];
  }
}

// ------------- gather-mean aggregation (no atomics) -------------
// 8 nodes per 256-thread block; 32 lanes per node, float4 per lane.
__global__ void k_agg(const floatx4* __restrict__ feat4, const int* __restrict__ rowStart,
                      const int* __restrict__ srcIdx, const float* __restrict__ invdeg,
                      floatx4* __restrict__ agg4, int n){
  int node = blockIdx.x*8 + (threadIdx.x >> 5);
  int f4 = threadIdx.x & 31;
  if (node >= n) return;
  int p0 = rowStart[node], p1 = rowStart[node+1];
  floatx4 acc = {0.f, 0.f, 0.f, 0.f};
  for (int p = p0; p < p1; ++p){
    int s = srcIdx[p];
    acc += feat4[s*32 + f4];
  }
  float sc = invdeg[node];
  acc *= sc;
  agg4[node*32 + f4] = acc;
}

// ------------- weight prep: Wcat[j][0:128]=wl[j][:], [128:256]=wr[j][:] (fp16) -------------
__global__ void k_prepw(const float* __restrict__ wl, const float* __restrict__ wr,
                        _Float16* __restrict__ Wcat){
  int idx = blockIdx.x*256 + threadIdx.x;   // 128*256 total
  int j = idx >> 8, k = idx & 255;
  float v = (k < 128) ? wl[j*128 + k] : wr[j*128 + (k - 128)];
  Wcat[idx] = (_Float16)v;
}

// ------------- fused GEMM: out[i][j] = act( [agg|x][i][:] . Wcat[j][:] + b[j] ) -------------
// Block: 256 threads (4 waves). Tile: 64 nodes x 64 j (blockIdx.y = j-half), K = 256.
// LDS 64KB exactly; XOR-swizzle (16B-chunk ^ row&7) for conflict-free b128 frag reads.
template<bool RELU>
__global__ __launch_bounds__(256) void k_gemm(
    const floatx4* __restrict__ Aagg4, const floatx4* __restrict__ Ax4,
    const half8* __restrict__ Wcat8, const float* __restrict__ bias,
    float* __restrict__ out, int n)
{
  __shared__ _Float16 Wl[64*256];
  __shared__ _Float16 Al[64*256];
  const int tid = threadIdx.x;
  const int node0 = blockIdx.x * 64;
  const int j0 = blockIdx.y * 64;

  // stage W half (64 rows x 32 chunks of 8 halfs)
  #pragma unroll
  for (int it = 0; it < 8; ++it){
    int chunk = it*256 + tid;                 // 0..2047
    int r = chunk >> 5, c = chunk & 31;
    half8 wv = Wcat8[(j0 + r)*32 + c];
    *(half8*)&Wl[r*256 + ((c ^ (r & 7)) << 3)] = wv;
  }
  // stage A = [agg | x] rows, fp32 -> fp16
  #pragma unroll
  for (int it = 0; it < 8; ++it){
    int chunk = it*256 + tid;                 // 0..2047
    int r = chunk >> 5, c = chunk & 31;
    int node = node0 + r;
    floatx4 v0 = {0,0,0,0}, v1 = {0,0,0,0};
    if (node < n){
      int kqa = 2*c, kqb = 2*c + 1;
      v0 = (kqa < 32) ? Aagg4[node*32 + kqa] : Ax4[node*32 + (kqa - 32)];
      v1 = (kqb < 32) ? Aagg4[node*32 + kqb] : Ax4[node*32 + (kqb - 32)];
    }
    half8 hv;
    hv[0] = (_Float16)v0[0]; hv[1] = (_Float16)v0[1];
    hv[2] = (_Float16)v0[2]; hv[3] = (_Float16)v0[3];
    hv[4] = (_Float16)v1[0]; hv[5] = (_Float16)v1[1];
    hv[6] = (_Float16)v1[2]; hv[7] = (_Float16)v1[3];
    *(half8*)&Al[r*256 + ((c ^ (r & 7)) << 3)] = hv;
  }
  __syncthreads();

  const int lane = tid & 63, wv = tid >> 6;
  const int m = lane & 15, quad = lane >> 4;
  floatx4 acc[4] = {{0,0,0,0},{0,0,0,0},{0,0,0,0},{0,0,0,0}};
  const int arow = wv*16 + m;

  #pragma unroll
  for (int ks = 0; ks < 8; ++ks){
    int ca = (ks*4 + quad) ^ (arow & 7);
    half8 a = *(const half8*)&Al[arow*256 + (ca << 3)];
    #pragma unroll
    for (int jt = 0; jt < 4; ++jt){
      int brow = jt*16 + m;
      int cb = (ks*4 + quad) ^ (brow & 7);
      half8 b = *(const half8*)&Wl[brow*256 + (cb << 3)];
      acc[jt] = __builtin_amdgcn_mfma_f32_16x16x32_f16(a, b, acc[jt], 0, 0, 0);
    }
  }

  #pragma unroll
  for (int jt = 0; jt < 4; ++jt){
    int j = j0 + jt*16 + m;
    float bj = bias[j];
    #pragma unroll
    for (int r = 0; r < 4; ++r){
      int node = node0 + wv*16 + quad*4 + r;
      if (node < n){
        float v = acc[jt][r] + bj;
        if (RELU) v = fmaxf(v, 0.f);
        out[node*DIM + j] = v;
      }
    }
  }
}

extern "C" void kernel_launch(void* const* d_in, const int* in_sizes, int n_in,
                              void* d_out, int out_size, void* d_ws, size_t ws_size,
                              hipStream_t stream)
{
  const float* x   = (const float*)d_in[0];
  const int*   ei  = (const int*)d_in[1];
  const float* w1l = (const float*)d_in[2];
  const float* b1  = (const float*)d_in[3];
  const float* w1r = (const float*)d_in[4];
  const float* w2l = (const float*)d_in[5];
  const float* b2  = (const float*)d_in[6];
  const float* w2r = (const float*)d_in[7];
  float* out = (float*)d_out;

  const int N = in_sizes[0] / DIM;
  const int E = in_sizes[1] / 2;

  char* p = (char*)d_ws;
  auto carve = [&](size_t bytes) -> char* {
    char* q = p;
    p += (bytes + 255) & ~(size_t)255;
    return q;
  };
  float*    agg       = (float*)carve((size_t)N * DIM * 4);
  float*    hbuf      = (float*)carve((size_t)N * DIM * 4);
  _Float16* Wc1       = (_Float16*)carve(128 * 256 * 2);
  _Float16* Wc2       = (_Float16*)carve(128 * 256 * 2);
  int*      deg       = (int*)carve((size_t)N * 4);
  int*      rowStart  = (int*)carve((size_t)(N + 1) * 4);
  int*      fill      = (int*)carve((size_t)N * 4);
  float*    invdeg    = (float*)carve((size_t)N * 4);
  int*      srcIdx    = (int*)carve((size_t)E * 4);
  int*      blockSums = (int*)carve(64 * 4);

  const int* src = ei;
  const int* dst = ei + E;

  hipMemsetAsync(deg, 0, (size_t)N * 4, stream);

  k_degree<<<(E + 255)/256, 256, 0, stream>>>(dst, deg, E);
  int nb = (N + 1023) / 1024;
  k_scan1<<<nb, 1024, 0, stream>>>(deg, rowStart, blockSums, N);
  k_scan2<<<1, 64, 0, stream>>>(blockSums, nb);
  k_scan3<<<nb, 1024, 0, stream>>>(rowStart, blockSums, fill, invdeg, deg, N, E);
  k_scatter<<<(E + 255)/256, 256, 0, stream>>>(src, dst, fill, srcIdx, E);

  k_prepw<<<128, 256, 0, stream>>>(w1l, w1r, Wc1);
  k_prepw<<<128, 256, 0, stream>>>(w2l, w2r, Wc2);

  dim3 gg((N + 63)/64, 2);
  // layer 1
  k_agg<<<(N + 7)/8, 256, 0, stream>>>((const floatx4*)x, rowStart, srcIdx, invdeg,
                                       (floatx4*)agg, N);
  k_gemm<true><<<gg, 256, 0, stream>>>((const floatx4*)agg, (const floatx4*)x,
                                       (const half8*)Wc1, b1, hbuf, N);
  // layer 2
  k_agg<<<(N + 7)/8, 256, 0, stream>>>((const floatx4*)hbuf, rowStart, srcIdx, invdeg,
                                       (floatx4*)agg, N);
  k_gemm<false><<<gg, 256, 0, stream>>>((const floatx4*)agg, (const floatx4*)hbuf,
                                        (const half8*)Wc2, b2, out, N);
}

// Round 2
// 250.797 us; speedup vs baseline: 1.2964x; 1.2964x over previous
//
#include <hip/hip_runtime.h>

#define DIM 128

typedef _Float16 half8 __attribute__((ext_vector_type(8)));
typedef float floatx4 __attribute__((ext_vector_type(4)));

// ---------------- CSR build ----------------
__global__ void k_degree(const int* __restrict__ dst, int* __restrict__ deg, int E){
  int e = blockIdx.x*256 + threadIdx.x;
  if (e < E) atomicAdd(&deg[dst[e]], 1);
}

__global__ void k_scan1(const int* __restrict__ deg, int* __restrict__ rowStart,
                        int* __restrict__ blockSums, int n){
  __shared__ int sm[16];
  int i = blockIdx.x*1024 + threadIdx.x;
  int v = (i < n) ? deg[i] : 0;
  int lane = threadIdx.x & 63, wid = threadIdx.x >> 6;
  int x = v;
  #pragma unroll
  for (int off = 1; off < 64; off <<= 1){
    int y = __shfl_up(x, off);
    if (lane >= off) x += y;
  }
  if (lane == 63) sm[wid] = x;
  __syncthreads();
  if (threadIdx.x < 64){
    int s = (lane < 16) ? sm[lane] : 0;
    #pragma unroll
    for (int off = 1; off < 16; off <<= 1){
      int y = __shfl_up(s, off);
      if (lane >= off) s += y;
    }
    if (lane < 16) sm[lane] = s;
  }
  __syncthreads();
  int base = (wid > 0) ? sm[wid-1] : 0;
  if (i < n) rowStart[i] = base + x - v;      // block-local exclusive
  if (threadIdx.x == 1023) blockSums[blockIdx.x] = sm[15];
}

__global__ void k_scan2(int* blockSums, int nb){   // 1 block, 64 threads, nb<=64
  int lane = threadIdx.x;
  int v = (lane < nb) ? blockSums[lane] : 0;
  int x = v;
  #pragma unroll
  for (int off = 1; off < 64; off <<= 1){
    int y = __shfl_up(x, off);
    if (lane >= off) x += y;
  }
  if (lane < nb) blockSums[lane] = x - v;     // exclusive
}

__global__ void k_scan3(int* __restrict__ rowStart, const int* __restrict__ blockSums,
                        int* __restrict__ fill, float* __restrict__ invdeg,
                        const int* __restrict__ deg, int n, int Etot){
  int i = blockIdx.x*1024 + threadIdx.x;
  if (i < n){
    int r = rowStart[i] + blockSums[i >> 10];
    rowStart[i] = r;
    fill[i] = r;
    invdeg[i] = 1.0f / fmaxf((float)deg[i], 1.0f);
  }
  if (i == 0) rowStart[n] = Etot;
}

__global__ void k_scatter(const int* __restrict__ src, const int* __restrict__ dst,
                          int* __restrict__ fill, int* __restrict__ srcIdx, int E){
  int e = blockIdx.x*256 + threadIdx.x;
  if (e < E){
    int p = atomicAdd(&fill[dst[e]], 1);
    srcIdx[p] = src[e];
  }
}

// ---------------- fp32 -> fp16 feature cast ----------------
__global__ void k_tohalf(const floatx4* __restrict__ in4, half8* __restrict__ out8, int n8){
  int i = blockIdx.x*256 + threadIdx.x;
  if (i < n8){
    floatx4 a = in4[2*i], b = in4[2*i + 1];
    half8 h;
    h[0] = (_Float16)a[0]; h[1] = (_Float16)a[1];
    h[2] = (_Float16)a[2]; h[3] = (_Float16)a[3];
    h[4] = (_Float16)b[0]; h[5] = (_Float16)b[1];
    h[6] = (_Float16)b[2]; h[7] = (_Float16)b[3];
    out8[i] = h;
  }
}

// ------------- gather-mean aggregation (fp16 rows, fp32 accumulate) -------------
// 16 nodes per 256-thread block; 16 lanes per node, half8 (16B) per lane.
__global__ void k_agg(const half8* __restrict__ featH8, const int* __restrict__ rowStart,
                      const int* __restrict__ srcIdx, const float* __restrict__ invdeg,
                      half8* __restrict__ aggH8, int n){
  int node = blockIdx.x*16 + (threadIdx.x >> 4);
  int l = threadIdx.x & 15;
  if (node >= n) return;
  int p0 = rowStart[node], p1 = rowStart[node+1];
  float acc[8] = {0,0,0,0,0,0,0,0};
  int p = p0;
  for (; p + 2 <= p1; p += 2){
    int s0 = srcIdx[p], s1 = srcIdx[p+1];
    half8 v0 = featH8[s0*16 + l];
    half8 v1 = featH8[s1*16 + l];
    #pragma unroll
    for (int i = 0; i < 8; ++i) acc[i] += (float)v0[i] + (float)v1[i];
  }
  if (p < p1){
    half8 v = featH8[srcIdx[p]*16 + l];
    #pragma unroll
    for (int i = 0; i < 8; ++i) acc[i] += (float)v[i];
  }
  float sc = invdeg[node];
  half8 o;
  #pragma unroll
  for (int i = 0; i < 8; ++i) o[i] = (_Float16)(acc[i]*sc);
  aggH8[node*16 + l] = o;
}

// ------------- weight prep: Wfrag in MFMA B-operand order -------------
// Wfrag[((ks*8 + jt)*64 + lane)][0:8] = Wcat[jt*16 + (lane&15)][ks*32 + (lane>>4)*8 + i]
// where Wcat[j][k] = k<128 ? wl[j][k] : wr[j][k-128].  64 KB per layer, L2-resident.
__global__ void k_prepw(const float* __restrict__ wl, const float* __restrict__ wr,
                        half8* __restrict__ Wf){
  int t = blockIdx.x*256 + threadIdx.x;   // 4096 = 8 ks * 8 jt * 64 lanes
  int ks = t >> 9, jt = (t >> 6) & 7, lane = t & 63;
  int j = jt*16 + (lane & 15);
  int kb = ks*32 + (lane >> 4)*8;
  half8 h;
  #pragma unroll
  for (int i = 0; i < 8; ++i){
    int k = kb + i;
    float v = (k < 128) ? wl[j*128 + k] : wr[j*128 + (k - 128)];
    h[i] = (_Float16)v;
  }
  Wf[t] = h;
}

// ------------- fused GEMM: out[i][j] = act( [agg|self][i][:] . Wcat[j][:] + b[j] ) -------------
// Block: 256 threads (4 waves). Tile: 64 nodes x FULL 128 j, K = 256.
// A (fp16) staged in 32KB LDS with XOR swizzle; B fragments streamed from
// L2-resident pre-swizzled Wfrag (no LDS, no duplication, coalesced half8 loads).
template<bool RELU, bool OUT_HALF>
__global__ __launch_bounds__(256) void k_gemm(
    const half8* __restrict__ aggH8, const half8* __restrict__ selfH8,
    const half8* __restrict__ Wf, const float* __restrict__ bias,
    void* __restrict__ outp, int n)
{
  __shared__ _Float16 Al[64*256];
  const int tid = threadIdx.x;
  const int node0 = blockIdx.x * 64;

  // stage A = [agg | self] rows, direct fp16 half8 loads
  #pragma unroll
  for (int it = 0; it < 8; ++it){
    int chunk = it*256 + tid;                 // 0..2047 = 64 rows x 32 chunks
    int r = chunk >> 5, c = chunk & 31;
    int node = node0 + r;
    half8 v = {};
    if (node < n) v = (c < 16) ? aggH8[node*16 + c] : selfH8[node*16 + (c - 16)];
    *(half8*)&Al[r*256 + ((c ^ (r & 7)) << 3)] = v;
  }
  __syncthreads();

  const int lane = tid & 63, wv = tid >> 6;
  const int m = lane & 15, quad = lane >> 4;
  const int arow = wv*16 + m;
  floatx4 acc[8] = {{0,0,0,0},{0,0,0,0},{0,0,0,0},{0,0,0,0},
                    {0,0,0,0},{0,0,0,0},{0,0,0,0},{0,0,0,0}};

  #pragma unroll
  for (int ks = 0; ks < 8; ++ks){
    int ca = ((ks*4 + quad) ^ (arow & 7)) << 3;
    half8 a = *(const half8*)&Al[arow*256 + ca];
    #pragma unroll
    for (int jt = 0; jt < 8; ++jt){
      half8 b = Wf[(ks*8 + jt)*64 + lane];
      acc[jt] = __builtin_amdgcn_mfma_f32_16x16x32_f16(a, b, acc[jt], 0, 0, 0);
    }
  }

  #pragma unroll
  for (int jt = 0; jt < 8; ++jt){
    int j = jt*16 + m;
    float bj = bias[j];
    #pragma unroll
    for (int r = 0; r < 4; ++r){
      int node = node0 + wv*16 + quad*4 + r;
      if (node < n){
        float v = acc[jt][r] + bj;
        if (RELU) v = fmaxf(v, 0.f);
        if (OUT_HALF) ((_Float16*)outp)[node*DIM + j] = (_Float16)v;
        else          ((float*)outp)[node*DIM + j] = v;
      }
    }
  }
}

extern "C" void kernel_launch(void* const* d_in, const int* in_sizes, int n_in,
                              void* d_out, int out_size, void* d_ws, size_t ws_size,
                              hipStream_t stream)
{
  const float* x   = (const float*)d_in[0];
  const int*   ei  = (const int*)d_in[1];
  const float* w1l = (const float*)d_in[2];
  const float* b1  = (const float*)d_in[3];
  const float* w1r = (const float*)d_in[4];
  const float* w2l = (const float*)d_in[5];
  const float* b2  = (const float*)d_in[6];
  const float* w2r = (const float*)d_in[7];
  float* out = (float*)d_out;

  const int N = in_sizes[0] / DIM;
  const int E = in_sizes[1] / 2;

  char* p = (char*)d_ws;
  auto carve = [&](size_t bytes) -> char* {
    char* q = p;
    p += (bytes + 255) & ~(size_t)255;
    return q;
  };
  _Float16* xh        = (_Float16*)carve((size_t)N * DIM * 2);
  _Float16* hh        = (_Float16*)carve((size_t)N * DIM * 2);
  _Float16* aggH      = (_Float16*)carve((size_t)N * DIM * 2);
  half8*    Wf1       = (half8*)carve(4096 * 16);
  half8*    Wf2       = (half8*)carve(4096 * 16);
  int*      deg       = (int*)carve((size_t)N * 4);
  int*      rowStart  = (int*)carve((size_t)(N + 1) * 4);
  int*      fill      = (int*)carve((size_t)N * 4);
  float*    invdeg    = (float*)carve((size_t)N * 4);
  int*      srcIdx    = (int*)carve((size_t)E * 4);
  int*      blockSums = (int*)carve(64 * 4);

  const int* src = ei;
  const int* dst = ei + E;

  hipMemsetAsync(deg, 0, (size_t)N * 4, stream);

  k_degree<<<(E + 255)/256, 256, 0, stream>>>(dst, deg, E);
  int nb = (N + 1023) / 1024;
  k_scan1<<<nb, 1024, 0, stream>>>(deg, rowStart, blockSums, N);
  k_scan2<<<1, 64, 0, stream>>>(blockSums, nb);
  k_scan3<<<nb, 1024, 0, stream>>>(rowStart, blockSums, fill, invdeg, deg, N, E);
  k_scatter<<<(E + 255)/256, 256, 0, stream>>>(src, dst, fill, srcIdx, E);

  int n8 = N * DIM / 8;
  k_tohalf<<<(n8 + 255)/256, 256, 0, stream>>>((const floatx4*)x, (half8*)xh, n8);
  k_prepw<<<16, 256, 0, stream>>>(w1l, w1r, Wf1);
  k_prepw<<<16, 256, 0, stream>>>(w2l, w2r, Wf2);

  int gAgg = (N + 15)/16;
  int gGemm = (N + 63)/64;
  // layer 1
  k_agg<<<gAgg, 256, 0, stream>>>((const half8*)xh, rowStart, srcIdx, invdeg,
                                  (half8*)aggH, N);
  k_gemm<true, true><<<gGemm, 256, 0, stream>>>((const half8*)aggH, (const half8*)xh,
                                                Wf1, b1, (void*)hh, N);
  // layer 2
  k_agg<<<gAgg, 256, 0, stream>>>((const half8*)hh, rowStart, srcIdx, invdeg,
                                  (half8*)aggH, N);
  k_gemm<false, false><<<gGemm, 256, 0, stream>>>((const half8*)aggH, (const half8*)hh,
                                                  Wf2, b2, (void*)out, N);
}

// Round 3
// 240.400 us; speedup vs baseline: 1.3525x; 1.0432x over previous
//
#include <hip/hip_runtime.h>

#define DIM 128

typedef _Float16 half8 __attribute__((ext_vector_type(8)));
typedef float floatx4 __attribute__((ext_vector_type(4)));

// ---------------- fused setup: zero deg + x->fp16 + weight-frag prep x2 ----------------
// block ranges: [0, bTohalf) cast, [bTohalf, bTohalf+32) prepw, rest zero deg.
__global__ void k_setup(const floatx4* __restrict__ in4, half8* __restrict__ out8,
                        const float* __restrict__ w1l, const float* __restrict__ w1r,
                        half8* __restrict__ Wf1,
                        const float* __restrict__ w2l, const float* __restrict__ w2r,
                        half8* __restrict__ Wf2,
                        int* __restrict__ deg, int n8, int n, int bTohalf){
  int b = blockIdx.x;
  if (b < bTohalf){
    int i = b*256 + threadIdx.x;
    if (i < n8){
      floatx4 a = in4[2*i], c = in4[2*i + 1];
      half8 h;
      h[0] = (_Float16)a[0]; h[1] = (_Float16)a[1];
      h[2] = (_Float16)a[2]; h[3] = (_Float16)a[3];
      h[4] = (_Float16)c[0]; h[5] = (_Float16)c[1];
      h[6] = (_Float16)c[2]; h[7] = (_Float16)c[3];
      out8[i] = h;
    }
  } else if (b < bTohalf + 32){
    int which = b - bTohalf;
    const float* wl = (which < 16) ? w1l : w2l;
    const float* wr = (which < 16) ? w1r : w2r;
    half8* Wf = (which < 16) ? Wf1 : Wf2;
    int t = (which & 15)*256 + threadIdx.x;   // 0..4095 = 8 ks * 8 jt * 64 lanes
    int ks = t >> 9, jt = (t >> 6) & 7, lane = t & 63;
    int j = jt*16 + (lane & 15);
    int kb = ks*32 + (lane >> 4)*8;
    half8 h;
    #pragma unroll
    for (int i = 0; i < 8; ++i){
      int k = kb + i;
      float v = (k < 128) ? wl[j*128 + k] : wr[j*128 + (k - 128)];
      h[i] = (_Float16)v;
    }
    Wf[t] = h;
  } else {
    int base = (b - bTohalf - 32)*1024 + threadIdx.x;
    #pragma unroll
    for (int k = 0; k < 4; ++k){
      int i = base + k*256;
      if (i < n) deg[i] = 0;
    }
  }
}

// ---------------- CSR build ----------------
__global__ void k_degree(const int* __restrict__ dst, int* __restrict__ deg, int E){
  int e = blockIdx.x*256 + threadIdx.x;
  if (e < E) atomicAdd(&deg[dst[e]], 1);
}

__global__ void k_scan1(const int* __restrict__ deg, int* __restrict__ rowStart,
                        int* __restrict__ blockSums, int n){
  __shared__ int sm[16];
  int i = blockIdx.x*1024 + threadIdx.x;
  int v = (i < n) ? deg[i] : 0;
  int lane = threadIdx.x & 63, wid = threadIdx.x >> 6;
  int x = v;
  #pragma unroll
  for (int off = 1; off < 64; off <<= 1){
    int y = __shfl_up(x, off);
    if (lane >= off) x += y;
  }
  if (lane == 63) sm[wid] = x;
  __syncthreads();
  if (threadIdx.x < 64){
    int s = (lane < 16) ? sm[lane] : 0;
    #pragma unroll
    for (int off = 1; off < 16; off <<= 1){
      int y = __shfl_up(s, off);
      if (lane >= off) s += y;
    }
    if (lane < 16) sm[lane] = s;
  }
  __syncthreads();
  int base = (wid > 0) ? sm[wid-1] : 0;
  if (i < n) rowStart[i] = base + x - v;      // block-local exclusive
  if (threadIdx.x == 1023) blockSums[blockIdx.x] = sm[15];
}

// scan2 folded in: each block sums blockSums[0..blockIdx.x) itself (nb <= 64).
__global__ void k_scan3(int* __restrict__ rowStart, const int* __restrict__ blockSums,
                        int* __restrict__ fill, float* __restrict__ invdeg,
                        const int* __restrict__ deg, int n, int Etot, int nb){
  __shared__ int basePre;
  int tid = threadIdx.x;
  if (tid < 64){
    int v = (tid < nb && tid < blockIdx.x) ? blockSums[tid] : 0;
    #pragma unroll
    for (int off = 32; off > 0; off >>= 1) v += __shfl_down(v, off);
    if (tid == 0) basePre = v;
  }
  __syncthreads();
  int i = blockIdx.x*1024 + tid;
  if (i < n){
    int r = rowStart[i] + basePre;
    rowStart[i] = r;
    fill[i] = r;
    invdeg[i] = 1.0f / fmaxf((float)deg[i], 1.0f);
  }
  if (i == 0) rowStart[n] = Etot;
}

__global__ void k_scatter(const int* __restrict__ src, const int* __restrict__ dst,
                          int* __restrict__ fill, int* __restrict__ srcIdx, int E){
  int e = blockIdx.x*256 + threadIdx.x;
  if (e < E){
    int p = atomicAdd(&fill[dst[e]], 1);
    srcIdx[p] = src[e];
  }
}

// ------------- fused gather-mean + GEMM -------------
// Block: 256 threads (4 waves), 64 nodes, full 128-j output, K=256 ([agg|self]).
// Phase 1: 16 lanes/node gather fp16 rows, fp32 accumulate, write fp16 into
//          XOR-swizzled LDS A-tile (cols 0..15 = agg, 16..31 = self).
// Phase 2: 16x16x32 MFMA vs L2-resident pre-swizzled W fragments (no LDS for B).
template<bool RELU, bool OUT_HALF>
__global__ __launch_bounds__(256) void k_agg_gemm(
    const half8* __restrict__ featH8, const int* __restrict__ rowStart,
    const int* __restrict__ srcIdx, const float* __restrict__ invdeg,
    const half8* __restrict__ Wf, const float* __restrict__ bias,
    void* __restrict__ outp, int n)
{
  __shared__ _Float16 Al[64*256];
  const int tid = threadIdx.x;
  const int node0 = blockIdx.x * 64;
  const int nl = tid >> 4;     // 0..15: node sub-group
  const int ch = tid & 15;     // 16-B chunk within row

  for (int pass = 0; pass < 4; ++pass){
    int r = pass*16 + nl;      // local row 0..63
    int node = node0 + r;
    half8 oa = {}, os = {};
    if (node < n){
      int p0 = rowStart[node], p1 = rowStart[node+1];
      float acc[8] = {0,0,0,0,0,0,0,0};
      int p = p0;
      for (; p + 4 <= p1; p += 4){
        int s0 = srcIdx[p], s1 = srcIdx[p+1], s2 = srcIdx[p+2], s3 = srcIdx[p+3];
        half8 v0 = featH8[s0*16 + ch];
        half8 v1 = featH8[s1*16 + ch];
        half8 v2 = featH8[s2*16 + ch];
        half8 v3 = featH8[s3*16 + ch];
        #pragma unroll
        for (int i = 0; i < 8; ++i)
          acc[i] += ((float)v0[i] + (float)v1[i]) + ((float)v2[i] + (float)v3[i]);
      }
      for (; p < p1; ++p){
        half8 v = featH8[srcIdx[p]*16 + ch];
        #pragma unroll
        for (int i = 0; i < 8; ++i) acc[i] += (float)v[i];
      }
      float sc = invdeg[node];
      #pragma unroll
      for (int i = 0; i < 8; ++i) oa[i] = (_Float16)(acc[i]*sc);
      os = featH8[node*16 + ch];
    }
    *(half8*)&Al[r*256 + ((ch        ^ (r & 7)) << 3)] = oa;
    *(half8*)&Al[r*256 + (((16 + ch) ^ (r & 7)) << 3)] = os;
  }
  __syncthreads();

  const int lane = tid & 63, wv = tid >> 6;
  const int m = lane & 15, quad = lane >> 4;
  const int arow = wv*16 + m;
  floatx4 acc[8] = {{0,0,0,0},{0,0,0,0},{0,0,0,0},{0,0,0,0},
                    {0,0,0,0},{0,0,0,0},{0,0,0,0},{0,0,0,0}};

  #pragma unroll
  for (int ks = 0; ks < 8; ++ks){
    int ca = ((ks*4 + quad) ^ (arow & 7)) << 3;
    half8 a = *(const half8*)&Al[arow*256 + ca];
    #pragma unroll
    for (int jt = 0; jt < 8; ++jt){
      half8 b = Wf[(ks*8 + jt)*64 + lane];
      acc[jt] = __builtin_amdgcn_mfma_f32_16x16x32_f16(a, b, acc[jt], 0, 0, 0);
    }
  }

  #pragma unroll
  for (int jt = 0; jt < 8; ++jt){
    int j = jt*16 + m;
    float bj = bias[j];
    #pragma unroll
    for (int r = 0; r < 4; ++r){
      int node = node0 + wv*16 + quad*4 + r;
      if (node < n){
        float v = acc[jt][r] + bj;
        if (RELU) v = fmaxf(v, 0.f);
        if (OUT_HALF) ((_Float16*)outp)[node*DIM + j] = (_Float16)v;
        else          ((float*)outp)[node*DIM + j] = v;
      }
    }
  }
}

extern "C" void kernel_launch(void* const* d_in, const int* in_sizes, int n_in,
                              void* d_out, int out_size, void* d_ws, size_t ws_size,
                              hipStream_t stream)
{
  const float* x   = (const float*)d_in[0];
  const int*   ei  = (const int*)d_in[1];
  const float* w1l = (const float*)d_in[2];
  const float* b1  = (const float*)d_in[3];
  const float* w1r = (const float*)d_in[4];
  const float* w2l = (const float*)d_in[5];
  const float* b2  = (const float*)d_in[6];
  const float* w2r = (const float*)d_in[7];
  float* out = (float*)d_out;

  const int N = in_sizes[0] / DIM;
  const int E = in_sizes[1] / 2;

  char* p = (char*)d_ws;
  auto carve = [&](size_t bytes) -> char* {
    char* q = p;
    p += (bytes + 255) & ~(size_t)255;
    return q;
  };
  _Float16* xh        = (_Float16*)carve((size_t)N * DIM * 2);
  _Float16* hh        = (_Float16*)carve((size_t)N * DIM * 2);
  half8*    Wf1       = (half8*)carve(4096 * 16);
  half8*    Wf2       = (half8*)carve(4096 * 16);
  int*      deg       = (int*)carve((size_t)N * 4);
  int*      rowStart  = (int*)carve((size_t)(N + 1) * 4);
  int*      fill      = (int*)carve((size_t)N * 4);
  float*    invdeg    = (float*)carve((size_t)N * 4);
  int*      srcIdx    = (int*)carve((size_t)E * 4);
  int*      blockSums = (int*)carve(64 * 4);

  const int* src = ei;
  const int* dst = ei + E;

  const int n8 = N * DIM / 8;
  const int bTohalf = (n8 + 255)/256;
  const int nb = (N + 1023)/1024;          // <= 64 required by k_scan3
  const int bZero = nb;                    // 1024 ints per block

  k_setup<<<bTohalf + 32 + bZero, 256, 0, stream>>>(
      (const floatx4*)x, (half8*)xh, w1l, w1r, Wf1, w2l, w2r, Wf2, deg, n8, N, bTohalf);

  k_degree<<<(E + 255)/256, 256, 0, stream>>>(dst, deg, E);
  k_scan1<<<nb, 1024, 0, stream>>>(deg, rowStart, blockSums, N);
  k_scan3<<<nb, 1024, 0, stream>>>(rowStart, blockSums, fill, invdeg, deg, N, E, nb);
  k_scatter<<<(E + 255)/256, 256, 0, stream>>>(src, dst, fill, srcIdx, E);

  int gGemm = (N + 63)/64;
  k_agg_gemm<true, true><<<gGemm, 256, 0, stream>>>(
      (const half8*)xh, rowStart, srcIdx, invdeg, Wf1, b1, (void*)hh, N);
  k_agg_gemm<false, false><<<gGemm, 256, 0, stream>>>(
      (const half8*)hh, rowStart, srcIdx, invdeg, Wf2, b2, (void*)out, N);
}